// Round 1
// baseline (371.832 us; speedup 1.0000x reference)
//
#include <hip/hip_runtime.h>

// Pillar scatter: out[b, f, y, x] += pillars[b, p, f] for pillars with
// contains_pillars[b,p]==1, y=coord[b,p,1], x=coord[b,p,2].
// Output [B, 64, 512, 512] fp32. Duplicate (y,x) per batch exist -> atomicAdd.

#define NF 64
#define XS 512
#define YS 512

__global__ void __launch_bounds__(256) pillar_scatter_kernel(
    const float* __restrict__ pillars,
    const int* __restrict__ coord,
    const int* __restrict__ contains,
    float* __restrict__ out,
    int BP, int P) {
  int gid = blockIdx.x * blockDim.x + threadIdx.x;
  int wave = gid >> 6;   // one wave per (b,p) pillar
  int lane = gid & 63;   // lane = feature index
  if (wave >= BP) return;
  // wave-uniform loads (broadcast through cache)
  if (contains[wave] == 0) return;
  int y = coord[wave * 3 + 1];
  int x = coord[wave * 3 + 2];
  int b = wave / P;
  float v = pillars[(size_t)wave * NF + lane];  // coalesced 256B per wave
  // out flat index: ((b*NF + f) * XS + y) * YS + x
  size_t oidx = (((size_t)(b * NF + lane)) << 18) + ((size_t)y << 9) + (size_t)x;
  atomicAdd(out + oidx, v);
}

extern "C" void kernel_launch(void* const* d_in, const int* in_sizes, int n_in,
                              void* d_out, int out_size, void* d_ws, size_t ws_size,
                              hipStream_t stream) {
  const float* pillars  = (const float*)d_in[0];
  const int*   coord    = (const int*)d_in[1];
  const int*   contains = (const int*)d_in[2];
  float* out = (float*)d_out;

  const int BP = in_sizes[2];                    // B * P
  const int B  = out_size / (NF * XS * YS);      // = 4
  const int P  = BP / B;                         // = 12000

  // Harness poisons d_out to 0xAA before every timed launch -> zero it.
  hipMemsetAsync(d_out, 0, (size_t)out_size * sizeof(float), stream);

  const int threads = BP * 64;                   // one wave per pillar
  const int block = 256;
  const int grid = (threads + block - 1) / block;
  pillar_scatter_kernel<<<grid, block, 0, stream>>>(pillars, coord, contains, out, BP, P);
}

// Round 2
// 296.255 us; speedup vs baseline: 1.2551x; 1.2551x over previous
//
#include <hip/hip_runtime.h>

// Pillar scatter, gather-formulated:
//   out[b, f, y, x] = sum over active pillars p with coord (y,x) of pillars[b,p,f]
// Output [B, 64, 512, 512] fp32 (268 MB). Only ~4.6% of cells occupied.
//
// Pass 1: slot[b][y*512+x] = one winning pillar gid (atomicExch); evicted
//         duplicates appended to overflow list.
// Pass 2: output-centric coalesced write of the whole grid (no memset needed):
//         each block = one (b,y) row; slot row staged in LDS; float4 stores.
// Pass 3: atomicAdd the few overflow pillars (duplicate cells).

#define NF 64
#define XS 512
#define YS 512
#define CELLS (XS * YS)        // 262144
#define OVCAP 16384            // overflow capacity (expected ~1k)

__global__ void __launch_bounds__(256) build_slots(
    const int* __restrict__ coord,
    const int* __restrict__ contains,
    int* __restrict__ slot,
    int* __restrict__ overflow,
    int* __restrict__ counter,
    int BP, int P) {
  int gid = blockIdx.x * 256 + threadIdx.x;
  if (gid >= BP) return;
  if (contains[gid] == 0) return;
  int y = coord[gid * 3 + 1];
  int x = coord[gid * 3 + 2];
  int b = gid / P;
  int cell = (b << 18) + (y << 9) + x;
  int old = atomicExch(slot + cell, gid);
  if (old >= 0) {                       // evicted a prior pillar -> overflow
    int k = atomicAdd(counter, 1);
    if (k < OVCAP) overflow[k] = old;
  }
}

__global__ void __launch_bounds__(256) fill_out(
    const float* __restrict__ pillars,
    const int* __restrict__ slot,
    float* __restrict__ out) {
  int by = blockIdx.x;          // [0, B*YS)
  int b = by >> 9;
  int y = by & 511;
  __shared__ int srow[XS];
  for (int i = threadIdx.x; i < XS; i += 256)
    srow[i] = slot[(b << 18) + (y << 9) + i];
  __syncthreads();
  int t = threadIdx.x;
  int x4 = (t & 127) << 2;      // 128 float4 positions cover 512 x
  int fbase = t >> 7;           // 0 or 1
  int s0 = srow[x4 + 0];
  int s1 = srow[x4 + 1];
  int s2 = srow[x4 + 2];
  int s3 = srow[x4 + 3];
  size_t rowoff = ((size_t)y << 9) + (size_t)x4;
#pragma unroll 4
  for (int fi = 0; fi < 32; ++fi) {
    int f = fi * 2 + fbase;
    float4 v;
    v.x = (s0 >= 0) ? pillars[((size_t)s0 << 6) + f] : 0.f;
    v.y = (s1 >= 0) ? pillars[((size_t)s1 << 6) + f] : 0.f;
    v.z = (s2 >= 0) ? pillars[((size_t)s2 << 6) + f] : 0.f;
    v.w = (s3 >= 0) ? pillars[((size_t)s3 << 6) + f] : 0.f;
    *(float4*)(out + (((size_t)(b * NF + f)) << 18) + rowoff) = v;
  }
}

__global__ void __launch_bounds__(256) fixup_overflow(
    const float* __restrict__ pillars,
    const int* __restrict__ coord,
    const int* __restrict__ overflow,
    const int* __restrict__ counter,
    float* __restrict__ out,
    int P) {
  int gid = blockIdx.x * 256 + threadIdx.x;
  int w = gid >> 6;
  int lane = gid & 63;
  int n = *counter;
  if (n > OVCAP) n = OVCAP;
  if (w >= n) return;
  int pg = overflow[w];
  int y = coord[pg * 3 + 1];
  int x = coord[pg * 3 + 2];
  int b = pg / P;
  atomicAdd(out + (((size_t)(b * NF + lane)) << 18) + ((size_t)y << 9) + x,
            pillars[((size_t)pg << 6) + lane]);
}

extern "C" void kernel_launch(void* const* d_in, const int* in_sizes, int n_in,
                              void* d_out, int out_size, void* d_ws, size_t ws_size,
                              hipStream_t stream) {
  const float* pillars  = (const float*)d_in[0];
  const int*   coord    = (const int*)d_in[1];
  const int*   contains = (const int*)d_in[2];
  float* out = (float*)d_out;

  const int BP = in_sizes[2];                    // B * P = 48000
  const int B  = out_size / (NF * CELLS);        // 4
  const int P  = BP / B;                         // 12000

  int* slot     = (int*)d_ws;                                  // B*CELLS ints = 4 MB
  int* counter  = (int*)((char*)d_ws + (size_t)B * CELLS * 4); // 1 int
  int* overflow = counter + 4;                                 // OVCAP ints

  // slots := -1 (0xFF bytes), counter := 0
  hipMemsetAsync(slot, 0xFF, (size_t)B * CELLS * 4, stream);
  hipMemsetAsync(counter, 0, 4, stream);

  build_slots<<<(BP + 255) / 256, 256, 0, stream>>>(coord, contains, slot,
                                                    overflow, counter, BP, P);
  fill_out<<<B * YS, 256, 0, stream>>>(pillars, slot, out);
  fixup_overflow<<<(OVCAP * 64) / 256, 256, 0, stream>>>(pillars, coord, overflow,
                                                         counter, out, P);
}

// Round 4
// 292.016 us; speedup vs baseline: 1.2733x; 1.0145x over previous
//
#include <hip/hip_runtime.h>

// Pillar scatter, gather-formulated with per-row binning:
//   out[b, f, y, x] = sum of pillars[b,p,:] over active pillars p at (y,x).
// Output [4, 64, 512, 512] fp32 (268 MB).
//
// Pass 1 (bin): active pillars appended to per-(b,y) row lists (atomicAdd on
//   2048 counters). Row overflow (>ROWCAP, never in practice) -> global list.
// Pass 2 (fill): one block per (b,y) row. Stage the row's pillar feature rows
//   in LDS (padded stride 65 -> no bank conflicts), build x->row map via LDS
//   CAS, merge duplicate-cell pillars in LDS, then write the full row across
//   all 64 feature planes with nontemporal float4 stores. No memset of d_out
//   needed -- every output element is written exactly once.
// Pass 3 (fixup): atomicAdd the (normally zero) overflow entries.

#define NF 64
#define XS 512
#define YS 512
#define ROWCAP 64            // max pillars staged per (b,y) row; mean ~12
#define OVCAP 16384

typedef float vf4 __attribute__((ext_vector_type(4)));  // native vec for nontemporal

__global__ void __launch_bounds__(256) bin_pillars(
    const int* __restrict__ coord,
    const int* __restrict__ contains,
    int* __restrict__ rowcnt,
    int* __restrict__ rowlist,
    int* __restrict__ ovcnt,
    int* __restrict__ ovlist,
    int BP, int P) {
  int gid = blockIdx.x * 256 + threadIdx.x;
  if (gid >= BP) return;
  if (contains[gid] == 0) return;
  int y = coord[gid * 3 + 1];
  int x = coord[gid * 3 + 2];
  int b = gid / P;
  int by = (b << 9) | y;
  int k = atomicAdd(rowcnt + by, 1);
  if (k < ROWCAP) {
    rowlist[by * ROWCAP + k] = (x << 16) | gid;   // gid < 48000 fits 16 bits
  } else {
    int o = atomicAdd(ovcnt, 1);
    if (o < OVCAP) ovlist[o] = gid;
  }
}

__global__ void __launch_bounds__(256) fill_out(
    const float* __restrict__ pillars,
    const int* __restrict__ rowcnt,
    const int* __restrict__ rowlist,
    float* __restrict__ out) {
  int by = blockIdx.x;            // [0, B*YS)
  int b = by >> 9;
  int y = by & 511;
  __shared__ int xmap[XS];                 // x -> staged row idx, or -1
  __shared__ float prow[ROWCAP * 65];      // staged pillar rows, stride 65 (pad)

  int t = threadIdx.x;
  xmap[t] = -1;
  xmap[t + 256] = -1;
  __syncthreads();

  int n = rowcnt[by];
  if (n > ROWCAP) n = ROWCAP;

  // claim cells; CAS losers are duplicate-cell pillars -> merge later
  int myold = -1;
  if (t < n) {
    int e = rowlist[by * ROWCAP + t];
    int x = e >> 16;
    myold = atomicCAS(&xmap[x], -1, t);    // >=0 means winner index
  }
  __syncthreads();

  // stage all listed pillar rows (coalesced 256B loads per row)
  int grp = t >> 6, lane = t & 63;
  for (int k = grp; k < n; k += 4) {
    int g = rowlist[by * ROWCAP + k] & 0xFFFF;
    prow[k * 65 + lane] = pillars[((size_t)g << 6) + lane];
  }
  __syncthreads();

  // merge duplicate cells into the winner's staged row (rare: ~0.13/row)
  if (myold >= 0) {
    for (int f = 0; f < NF; ++f)
      atomicAdd(&prow[myold * 65 + f], prow[t * 65 + f]);
  }
  __syncthreads();

  // emit: 128 float4 x-positions x 64 feature planes
  int x4 = (t & 127) << 2;
  int fbase = t >> 7;
  int s0 = xmap[x4 + 0];
  int s1 = xmap[x4 + 1];
  int s2 = xmap[x4 + 2];
  int s3 = xmap[x4 + 3];
  size_t rowoff = ((size_t)y << 9) + (size_t)x4;
#pragma unroll 4
  for (int fi = 0; fi < 32; ++fi) {
    int f = fi * 2 + fbase;
    vf4 v;
    v.x = (s0 >= 0) ? prow[s0 * 65 + f] : 0.f;
    v.y = (s1 >= 0) ? prow[s1 * 65 + f] : 0.f;
    v.z = (s2 >= 0) ? prow[s2 * 65 + f] : 0.f;
    v.w = (s3 >= 0) ? prow[s3 * 65 + f] : 0.f;
    __builtin_nontemporal_store(v, (vf4*)(out + (((size_t)(b * NF + f)) << 18) + rowoff));
  }
}

__global__ void __launch_bounds__(256) fixup_overflow(
    const float* __restrict__ pillars,
    const int* __restrict__ coord,
    const int* __restrict__ ovlist,
    const int* __restrict__ ovcnt,
    float* __restrict__ out,
    int P) {
  int gid = blockIdx.x * 256 + threadIdx.x;
  int w = gid >> 6;
  int lane = gid & 63;
  int n = *ovcnt;
  if (n > OVCAP) n = OVCAP;
  int nw = gridDim.x * 4;   // total waves
  for (int i = w; i < n; i += nw) {
    int g = ovlist[i];
    int y = coord[g * 3 + 1];
    int x = coord[g * 3 + 2];
    int b = g / P;
    atomicAdd(out + (((size_t)(b * NF + lane)) << 18) + ((size_t)y << 9) + x,
              pillars[((size_t)g << 6) + lane]);
  }
}

extern "C" void kernel_launch(void* const* d_in, const int* in_sizes, int n_in,
                              void* d_out, int out_size, void* d_ws, size_t ws_size,
                              hipStream_t stream) {
  const float* pillars  = (const float*)d_in[0];
  const int*   coord    = (const int*)d_in[1];
  const int*   contains = (const int*)d_in[2];
  float* out = (float*)d_out;

  const int BP = in_sizes[2];                    // B * P = 48000
  const int B  = out_size / (NF * XS * YS);      // 4
  const int P  = BP / B;                         // 12000
  const int NROW = B * YS;                       // 2048

  // workspace layout: [rowcnt 2048 ints][ovcnt 1 int + pad][rowlist][ovlist]
  int* rowcnt  = (int*)d_ws;
  int* ovcnt   = rowcnt + NROW;
  int* rowlist = ovcnt + 4;
  int* ovlist  = rowlist + NROW * ROWCAP;

  // one small clear covers rowcnt + ovcnt
  (void)hipMemsetAsync(rowcnt, 0, (size_t)(NROW + 4) * sizeof(int), stream);

  bin_pillars<<<(BP + 255) / 256, 256, 0, stream>>>(coord, contains, rowcnt,
                                                    rowlist, ovcnt, ovlist, BP, P);
  fill_out<<<NROW, 256, 0, stream>>>(pillars, rowcnt, rowlist, out);
  fixup_overflow<<<64, 256, 0, stream>>>(pillars, coord, ovlist, ovcnt, out, P);
}